// Round 1
// baseline (6153.308 us; speedup 1.0000x reference)
//
#include <hip/hip_runtime.h>
#include <math.h>

#define S_LEN 1024
#define B_SZ 2
#define H_DIM 1024
#define NHQ 8
#define NKV 2
#define D_HEAD 128
#define NE 64
#define TOPK 8
#define NGRP 8
#define TGRP 4
#define FI_DIM 512
#define CAP 512
#define EPS_F 1e-5f
#define T_TOK (B_SZ * S_LEN)              // 2048
#define QKV_DIM ((NHQ + 2 * NKV) * D_HEAD) // 1536
#define SCALE_F 0.08838834764831845f       // 1/sqrt(128)

// ---------------- RMSNorm over a full H=1024 row ----------------
__global__ __launch_bounds__(256) void rmsnorm_row(const float* __restrict__ x,
                                                   const float* __restrict__ w,
                                                   float* __restrict__ out) {
  int t = blockIdx.x;
  int tid = threadIdx.x;
  const float* xp = x + (size_t)t * H_DIM;
  float4 v = *(const float4*)(xp + tid * 4);
  float ss = v.x * v.x + v.y * v.y + v.z * v.z + v.w * v.w;
  for (int i = 1; i < 64; i <<= 1) ss += __shfl_xor(ss, i);
  __shared__ float red[4];
  if ((tid & 63) == 0) red[tid >> 6] = ss;
  __syncthreads();
  float tot = red[0] + red[1] + red[2] + red[3];
  float rs = rsqrtf(tot / (float)H_DIM + EPS_F);
  float4 wv = *(const float4*)(w + tid * 4);
  float4 o;
  o.x = v.x * rs * wv.x; o.y = v.y * rs * wv.y;
  o.z = v.z * rs * wv.z; o.w = v.w * rs * wv.w;
  *(float4*)(out + (size_t)t * H_DIM + tid * 4) = o;
}

// ---------------- Generic NT GEMM: C[M,N] = A[M,K] @ W[N,K]^T (+bias)(+res) ----------------
__global__ __launch_bounds__(256) void gemm_nt(const float* __restrict__ A,
                                               const float* __restrict__ W,
                                               const float* __restrict__ bias,
                                               const float* __restrict__ res,
                                               float* __restrict__ C,
                                               int M, int N, int K) {
  __shared__ float As[16][64];
  __shared__ float Bs[16][64];
  int tid = threadIdx.x;
  int m0 = blockIdx.y * 64, n0 = blockIdx.x * 64;
  int lr = tid >> 2;
  int lc = (tid & 3) << 2;
  int tm = (tid >> 4) << 2;
  int tn = (tid & 15) << 2;
  float acc[4][4] = {{0.f}};
  for (int k0 = 0; k0 < K; k0 += 16) {
    float4 av = *(const float4*)(A + (size_t)(m0 + lr) * K + k0 + lc);
    float4 wv = *(const float4*)(W + (size_t)(n0 + lr) * K + k0 + lc);
    As[lc + 0][lr] = av.x; As[lc + 1][lr] = av.y; As[lc + 2][lr] = av.z; As[lc + 3][lr] = av.w;
    Bs[lc + 0][lr] = wv.x; Bs[lc + 1][lr] = wv.y; Bs[lc + 2][lr] = wv.z; Bs[lc + 3][lr] = wv.w;
    __syncthreads();
#pragma unroll
    for (int kk = 0; kk < 16; ++kk) {
      float a0 = As[kk][tm], a1 = As[kk][tm + 1], a2 = As[kk][tm + 2], a3 = As[kk][tm + 3];
      float b0 = Bs[kk][tn], b1 = Bs[kk][tn + 1], b2 = Bs[kk][tn + 2], b3 = Bs[kk][tn + 3];
      acc[0][0] = fmaf(a0, b0, acc[0][0]); acc[0][1] = fmaf(a0, b1, acc[0][1]);
      acc[0][2] = fmaf(a0, b2, acc[0][2]); acc[0][3] = fmaf(a0, b3, acc[0][3]);
      acc[1][0] = fmaf(a1, b0, acc[1][0]); acc[1][1] = fmaf(a1, b1, acc[1][1]);
      acc[1][2] = fmaf(a1, b2, acc[1][2]); acc[1][3] = fmaf(a1, b3, acc[1][3]);
      acc[2][0] = fmaf(a2, b0, acc[2][0]); acc[2][1] = fmaf(a2, b1, acc[2][1]);
      acc[2][2] = fmaf(a2, b2, acc[2][2]); acc[2][3] = fmaf(a2, b3, acc[2][3]);
      acc[3][0] = fmaf(a3, b0, acc[3][0]); acc[3][1] = fmaf(a3, b1, acc[3][1]);
      acc[3][2] = fmaf(a3, b2, acc[3][2]); acc[3][3] = fmaf(a3, b3, acc[3][3]);
    }
    __syncthreads();
  }
#pragma unroll
  for (int i = 0; i < 4; ++i) {
    int m = m0 + tm + i;
#pragma unroll
    for (int j = 0; j < 4; ++j) {
      int n = n0 + tn + j;
      float v = acc[i][j];
      if (bias) v += bias[n];
      if (res) v += res[(size_t)m * N + n];
      C[(size_t)m * N + n] = v;
    }
  }
}

// ---------------- per-head q/k RMSNorm + partial rope (first 64 dims), in-place on qkv ----------------
__global__ __launch_bounds__(64) void qknorm_rope(float* __restrict__ qkv,
                                                  const int* __restrict__ positions,
                                                  const float* __restrict__ qn_w,
                                                  const float* __restrict__ kn_w) {
  int t = blockIdx.x;
  int head = blockIdx.y;   // 0..7 q heads, 8..9 k heads
  int lane = threadIdx.x;  // 64
  int s = t & (S_LEN - 1);
  bool isq = head < NHQ;
  int off = isq ? head * D_HEAD : (NHQ * D_HEAD + (head - NHQ) * D_HEAD);
  float* ptr = qkv + (size_t)t * QKV_DIM + off;
  const float* w = isq ? qn_w : kn_w;
  float x0 = ptr[lane];
  float x1 = ptr[lane + 64];
  float ss = x0 * x0 + x1 * x1;
  for (int i = 1; i < 64; i <<= 1) ss += __shfl_xor(ss, i);
  float rs = rsqrtf(ss / (float)D_HEAD + EPS_F);
  x0 = x0 * rs * w[lane];
  x1 = x1 * rs * w[lane + 64];
  // rope on dims 0..63 (x0); dims 64..127 pass through
  float pos = (float)positions[s];
  int i2 = lane & 31;
  float invf = powf(10000.0f, -(float)i2 / 32.0f);
  float ang = pos * invf;
  float c = cosf(ang), sn = sinf(ang);
  float other = __shfl_xor(x0, 32);
  float r = (lane < 32) ? (x0 * c - other * sn) : (x0 * c + other * sn);
  ptr[lane] = r;
  ptr[lane + 64] = x1;
}

// ---------------- causal GQA attention, one block per (q,h,b) ----------------
__global__ __launch_bounds__(256) void attn_kernel(const float* __restrict__ qkv,
                                                   float* __restrict__ attnout) {
  int q = blockIdx.x, h = blockIdx.y, b = blockIdx.z;
  int tid = threadIdx.x;
  __shared__ float qs[D_HEAD];
  __shared__ float ps[S_LEN];
  __shared__ float red[256];
  int kvh = h >> 2;  // NH/NKV = 4
  const float* qptr = qkv + ((size_t)(b * S_LEN + q)) * QKV_DIM + h * D_HEAD;
  if (tid < D_HEAD) qs[tid] = qptr[tid];
  __syncthreads();
  int nk = q + 1;
  float lmax = -1e30f;
  for (int k = tid; k < nk; k += 256) {
    const float* kptr = qkv + ((size_t)(b * S_LEN + k)) * QKV_DIM + NHQ * D_HEAD + kvh * D_HEAD;
    float sacc = 0.f;
#pragma unroll
    for (int d = 0; d < D_HEAD; d += 4) {
      float4 kv4 = *(const float4*)(kptr + d);
      sacc = fmaf(qs[d], kv4.x, sacc);
      sacc = fmaf(qs[d + 1], kv4.y, sacc);
      sacc = fmaf(qs[d + 2], kv4.z, sacc);
      sacc = fmaf(qs[d + 3], kv4.w, sacc);
    }
    sacc *= SCALE_F;
    ps[k] = sacc;
    lmax = fmaxf(lmax, sacc);
  }
  red[tid] = lmax;
  __syncthreads();
  for (int s2 = 128; s2 > 0; s2 >>= 1) {
    if (tid < s2) red[tid] = fmaxf(red[tid], red[tid + s2]);
    __syncthreads();
  }
  float m = red[0];
  __syncthreads();
  float lsum = 0.f;
  for (int k = tid; k < nk; k += 256) {
    float e = expf(ps[k] - m);
    ps[k] = e;
    lsum += e;
  }
  red[tid] = lsum;
  __syncthreads();
  for (int s2 = 128; s2 > 0; s2 >>= 1) {
    if (tid < s2) red[tid] += red[tid + s2];
    __syncthreads();
  }
  float inv = 1.0f / red[0];
  __syncthreads();
  // PV: threads 0..127 dim d (half 0), 128..255 dim d (half 1)
  int d = tid & 127, half = tid >> 7;
  float acc = 0.f;
  for (int k = half; k < nk; k += 2) {
    const float* vptr = qkv + ((size_t)(b * S_LEN + k)) * QKV_DIM + (NHQ + NKV) * D_HEAD + kvh * D_HEAD;
    acc = fmaf(ps[k], vptr[d], acc);
  }
  red[tid] = acc;
  __syncthreads();
  if (tid < 128) {
    float o = (red[tid] + red[tid + 128]) * inv;
    attnout[((size_t)(b * S_LEN + q)) * (NHQ * D_HEAD) + h * D_HEAD + d] = o;
  }
}

// ---------------- MoE gating: sigmoid gate, group top-2/top-4, masked top-8 ----------------
__global__ __launch_bounds__(64) void gating_kernel(const float* __restrict__ xt,
                                                    const float* __restrict__ gate_w,
                                                    const float* __restrict__ gate_b,
                                                    int* __restrict__ topi,
                                                    float* __restrict__ fw) {
  __shared__ float xs[H_DIM];
  __shared__ float sc[NE];
  __shared__ float corr[NE];
  __shared__ float grp[NGRP];
  int t = blockIdx.x;
  int e = threadIdx.x;
  for (int i = e; i < H_DIM; i += 64) xs[i] = xt[(size_t)t * H_DIM + i];
  __syncthreads();
  const float* gw = gate_w + (size_t)e * H_DIM;
  float acc = 0.f;
  for (int h = 0; h < H_DIM; ++h) acc = fmaf(xs[h], gw[h], acc);
  float s = 1.f / (1.f + expf(-acc));
  sc[e] = s;
  corr[e] = s + gate_b[e];
  __syncthreads();
  if (e < NGRP) {
    float m1 = -1e30f, m2 = -1e30f;
    for (int j = 0; j < NE / NGRP; ++j) {
      float v = corr[e * 8 + j];
      if (v > m1) { m2 = m1; m1 = v; }
      else if (v > m2) m2 = v;
    }
    grp[e] = m1 + m2;
  }
  __syncthreads();
  if (e == 0) {
    bool gsel[NGRP];
    for (int g = 0; g < NGRP; ++g) gsel[g] = false;
    for (int it = 0; it < TGRP; ++it) {
      int bi = -1; float bv = -1e30f;
      for (int g = 0; g < NGRP; ++g)
        if (!gsel[g] && grp[g] > bv) { bv = grp[g]; bi = g; }
      gsel[bi] = true;
    }
    bool ch[NE];
    for (int i2 = 0; i2 < NE; ++i2) ch[i2] = false;
    int sel[TOPK];
    float wsum = 0.f;
    for (int it = 0; it < TOPK; ++it) {
      int bi = -1; float bv = -1e30f;
      for (int x2 = 0; x2 < NE; ++x2) {
        if (!gsel[x2 >> 3] || ch[x2]) continue;
        if (corr[x2] > bv) { bv = corr[x2]; bi = x2; }
      }
      ch[bi] = true;
      sel[it] = bi;
      wsum += sc[bi];
    }
    float inv = 1.f / wsum;
    for (int it = 0; it < TOPK; ++it) {
      topi[t * TOPK + it] = sel[it];
      fw[t * TOPK + it] = sc[sel[it]] * inv;
    }
  }
}

// ---------------- ordered capacity scan: exact flattened-order pos_e ----------------
__global__ __launch_bounds__(64) void scan_kernel(const int* __restrict__ topi,
                                                  int* __restrict__ perm,
                                                  int* __restrict__ ecnt) {
  int e = threadIdx.x;
  int cnt = 0;
  for (int i = 0; i < T_TOK * TOPK; ++i) {
    if (topi[i] == e) {
      if (cnt < CAP) perm[e * CAP + cnt] = i;
      cnt++;
    }
  }
  ecnt[e] = cnt < CAP ? cnt : CAP;
}

// ---------------- zero helper ----------------
__global__ void zero_kernel(float4* __restrict__ p) {
  p[(size_t)blockIdx.x * 256 + threadIdx.x] = make_float4(0.f, 0.f, 0.f, 0.f);
}

// ---------------- fused expert FFN: gu = x@Wgu ; act = silu(g)*u ; out += (act@Wdn)*w ----------------
// 16 rows per block, dynamic LDS 64 KB. shared_mode=1: identity rows, weight 1.
__global__ __launch_bounds__(256) void ffn_kernel(const float* __restrict__ xt,
                                                  const float* __restrict__ wgu_all,
                                                  const float* __restrict__ wdn_all,
                                                  const int* __restrict__ perm,
                                                  const int* __restrict__ ecnt,
                                                  const float* __restrict__ fw,
                                                  float* __restrict__ outacc,
                                                  int shared_mode) {
  extern __shared__ float smem[];  // 16 * 1024 floats
  int tid = threadIdx.x;
  int e = blockIdx.y;
  int base = blockIdx.x * 16;
  int cnt = shared_mode ? T_TOK : ecnt[e];
  if (base >= cnt) return;
  int rows = cnt - base;
  if (rows > 16) rows = 16;
  const float* wg = shared_mode ? wgu_all : wgu_all + (size_t)e * H_DIM * (2 * FI_DIM);
  const float* wd = shared_mode ? wdn_all : wdn_all + (size_t)e * FI_DIM * H_DIM;

  for (int idx = tid; idx < 16 * 1024; idx += 256) {
    int r = idx >> 10;
    float v = 0.f;
    if (r < rows) {
      int tt = shared_mode ? (base + r) : (perm[e * CAP + base + r] >> 3);
      v = xt[(size_t)tt * H_DIM + (idx & 1023)];
    }
    smem[idx] = v;
  }
  __syncthreads();

  float acc[16][4];
#pragma unroll
  for (int r = 0; r < 16; ++r) { acc[r][0] = 0.f; acc[r][1] = 0.f; acc[r][2] = 0.f; acc[r][3] = 0.f; }
  for (int hh = 0; hh < H_DIM; ++hh) {
    const float* wrow = wg + (size_t)hh * (2 * FI_DIM);
    float w0 = wrow[tid];
    float w1 = wrow[256 + tid];
    float w2 = wrow[512 + tid];
    float w3 = wrow[768 + tid];
#pragma unroll
    for (int r = 0; r < 16; ++r) {
      float xv = smem[(r << 10) + hh];
      acc[r][0] = fmaf(xv, w0, acc[r][0]);
      acc[r][1] = fmaf(xv, w1, acc[r][1]);
      acc[r][2] = fmaf(xv, w2, acc[r][2]);
      acc[r][3] = fmaf(xv, w3, acc[r][3]);
    }
  }
  __syncthreads();  // all x reads done; overwrite with gu
#pragma unroll
  for (int r = 0; r < 16; ++r) {
    smem[(r << 10) + tid] = acc[r][0];
    smem[(r << 10) + 256 + tid] = acc[r][1];
    smem[(r << 10) + 512 + tid] = acc[r][2];
    smem[(r << 10) + 768 + tid] = acc[r][3];
  }
  __syncthreads();
  // act in place: act[f] = silu(gu[f]) * gu[512+f], f in [0,512)
#pragma unroll
  for (int j = 0; j < 2; ++j) {
    int f = j * 256 + tid;
#pragma unroll
    for (int r = 0; r < 16; ++r) {
      float g = smem[(r << 10) + f];
      float u = smem[(r << 10) + 512 + f];
      smem[(r << 10) + f] = (g / (1.f + expf(-g))) * u;
    }
  }
  __syncthreads();
  float acc2[16][4];
#pragma unroll
  for (int r = 0; r < 16; ++r) { acc2[r][0] = 0.f; acc2[r][1] = 0.f; acc2[r][2] = 0.f; acc2[r][3] = 0.f; }
  for (int f = 0; f < FI_DIM; ++f) {
    const float* wrow = wd + (size_t)f * H_DIM;
    float w0 = wrow[tid];
    float w1 = wrow[256 + tid];
    float w2 = wrow[512 + tid];
    float w3 = wrow[768 + tid];
#pragma unroll
    for (int r = 0; r < 16; ++r) {
      float av = smem[(r << 10) + f];
      acc2[r][0] = fmaf(av, w0, acc2[r][0]);
      acc2[r][1] = fmaf(av, w1, acc2[r][1]);
      acc2[r][2] = fmaf(av, w2, acc2[r][2]);
      acc2[r][3] = fmaf(av, w3, acc2[r][3]);
    }
  }
  for (int r = 0; r < rows; ++r) {
    int tt;
    float wt;
    if (shared_mode) { tt = base + r; wt = 1.f; }
    else {
      int fi = perm[e * CAP + base + r];
      tt = fi >> 3;
      wt = fw[fi];
    }
    float* op = outacc + (size_t)tt * H_DIM;
    unsafeAtomicAdd(op + tid, acc2[r][0] * wt);
    unsafeAtomicAdd(op + 256 + tid, acc2[r][1] * wt);
    unsafeAtomicAdd(op + 512 + tid, acc2[r][2] * wt);
    unsafeAtomicAdd(op + 768 + tid, acc2[r][3] * wt);
  }
}

// ---------------- final combine: out = h2 + (routed + shared) ----------------
__global__ void combine_kernel(const float4* __restrict__ a, const float4* __restrict__ b,
                               float4* __restrict__ o) {
  size_t i = (size_t)blockIdx.x * 256 + threadIdx.x;
  float4 x = a[i], y = b[i];
  o[i] = make_float4(x.x + y.x, x.y + y.y, x.z + y.z, x.w + y.w);
}

extern "C" void kernel_launch(void* const* d_in, const int* in_sizes, int n_in,
                              void* d_out, int out_size, void* d_ws, size_t ws_size,
                              hipStream_t stream) {
  const float* x = (const float*)d_in[0];
  const int* positions = (const int*)d_in[1];
  const float* ln1_w = (const float*)d_in[2];
  const float* ln2_w = (const float*)d_in[3];
  const float* wqkv = (const float*)d_in[4];
  const float* bqkv = (const float*)d_in[5];
  const float* qn_w = (const float*)d_in[6];
  const float* kn_w = (const float*)d_in[7];
  const float* wo = (const float*)d_in[8];
  const float* gate_w = (const float*)d_in[9];
  const float* gate_b = (const float*)d_in[10];
  const float* w_gu = (const float*)d_in[11];
  const float* w_dn = (const float*)d_in[12];
  const float* sw_gu = (const float*)d_in[13];
  const float* sw_dn = (const float*)d_in[14];
  float* out = (float*)d_out;

  float* ws = (float*)d_ws;
  float* h1 = ws;                       // T*H = 2,097,152
  float* qkv = h1 + 2097152;            // T*1536 = 3,145,728
  float* attnout = qkv + 3145728;       // 2,097,152
  float* h2 = attnout + 2097152;        // 2,097,152
  float* xt = h2 + 2097152;             // 2,097,152
  float* moe_acc = xt + 2097152;        // 2,097,152
  float* fw = moe_acc + 2097152;        // 16,384
  int* topi = (int*)(fw + 16384);       // 16,384
  int* perm = topi + 16384;             // 32,768
  int* ecnt = perm + 32768;             // 64

  // 1. rmsnorm(x, ln1_w)
  rmsnorm_row<<<T_TOK, 256, 0, stream>>>(x, ln1_w, h1);
  // 2. qkv = h1 @ wqkv^T + bqkv
  gemm_nt<<<dim3(QKV_DIM / 64, T_TOK / 64), 256, 0, stream>>>(h1, wqkv, bqkv, nullptr, qkv,
                                                              T_TOK, QKV_DIM, H_DIM);
  // 3. per-head q/k rmsnorm + rope (in place)
  qknorm_rope<<<dim3(T_TOK, NHQ + NKV), 64, 0, stream>>>(qkv, positions, qn_w, kn_w);
  // 4. causal GQA attention
  attn_kernel<<<dim3(S_LEN, NHQ, B_SZ), 256, 0, stream>>>(qkv, attnout);
  // 5. h2 = x + attnout @ wo^T
  gemm_nt<<<dim3(H_DIM / 64, T_TOK / 64), 256, 0, stream>>>(attnout, wo, nullptr, x, h2,
                                                            T_TOK, H_DIM, NHQ * D_HEAD);
  // 6. xt = rmsnorm(h2, ln2_w)
  rmsnorm_row<<<T_TOK, 256, 0, stream>>>(h2, ln2_w, xt);
  // 7. gating
  gating_kernel<<<T_TOK, 64, 0, stream>>>(xt, gate_w, gate_b, topi, fw);
  // 8. zero MoE accumulator (ws is poisoned each call)
  zero_kernel<<<2048, 256, 0, stream>>>((float4*)moe_acc);
  // 9. ordered capacity scan
  scan_kernel<<<1, 64, 0, stream>>>(topi, perm, ecnt);
  // 10. routed experts
  ffn_kernel<<<dim3(CAP / 16, NE), 256, 65536, stream>>>(xt, w_gu, w_dn, perm, ecnt, fw,
                                                         moe_acc, 0);
  // 11. shared expert
  ffn_kernel<<<dim3(T_TOK / 16, 1), 256, 65536, stream>>>(xt, sw_gu, sw_dn, nullptr, nullptr,
                                                          nullptr, moe_acc, 1);
  // 12. out = h2 + moe_acc
  combine_kernel<<<2048, 256, 0, stream>>>((const float4*)h2, (const float4*)moe_acc,
                                           (float4*)out);
}

// Round 2
// 4183.971 us; speedup vs baseline: 1.4707x; 1.4707x over previous
//
#include <hip/hip_runtime.h>
#include <math.h>

#define S_LEN 1024
#define B_SZ 2
#define H_DIM 1024
#define NHQ 8
#define NKV 2
#define D_HEAD 128
#define NE 64
#define TOPK 8
#define NGRP 8
#define TGRP 4
#define FI_DIM 512
#define CAP 512
#define EPS_F 1e-5f
#define T_TOK (B_SZ * S_LEN)               // 2048
#define QKV_DIM ((NHQ + 2 * NKV) * D_HEAD) // 1536
#define SCALE_F 0.08838834764831845f       // 1/sqrt(128)

typedef __attribute__((ext_vector_type(8))) short short8;
typedef __attribute__((ext_vector_type(4))) float floatx4;

__device__ inline short f2bf(float f) {
  union { float f; unsigned u; } v; v.f = f;
  unsigned r = (v.u + 0x7FFFu + ((v.u >> 16) & 1u)) >> 16;
  return (short)(r & 0xFFFFu);
}
__device__ inline float bf2f(short s) {
  union { unsigned u; float f; } v; v.u = ((unsigned)(unsigned short)s) << 16;
  return v.f;
}

// ---------------- RMSNorm: writes bf16 always, fp32 optionally ----------------
__global__ __launch_bounds__(256) void rmsnorm_row(const float* __restrict__ x,
                                                   const float* __restrict__ w,
                                                   float* __restrict__ outf,
                                                   short* __restrict__ outb) {
  int t = blockIdx.x;
  int tid = threadIdx.x;
  const float* xp = x + (size_t)t * H_DIM;
  float4 v = *(const float4*)(xp + tid * 4);
  float ss = v.x * v.x + v.y * v.y + v.z * v.z + v.w * v.w;
  for (int i = 1; i < 64; i <<= 1) ss += __shfl_xor(ss, i);
  __shared__ float red[4];
  if ((tid & 63) == 0) red[tid >> 6] = ss;
  __syncthreads();
  float tot = red[0] + red[1] + red[2] + red[3];
  float rs = rsqrtf(tot / (float)H_DIM + EPS_F);
  float4 wv = *(const float4*)(w + tid * 4);
  float4 o;
  o.x = v.x * rs * wv.x; o.y = v.y * rs * wv.y;
  o.z = v.z * rs * wv.z; o.w = v.w * rs * wv.w;
  if (outf) *(float4*)(outf + (size_t)t * H_DIM + tid * 4) = o;
  short* bp = outb + (size_t)t * H_DIM + tid * 4;
  bp[0] = f2bf(o.x); bp[1] = f2bf(o.y); bp[2] = f2bf(o.z); bp[3] = f2bf(o.w);
}

// ---------------- MFMA NT GEMM: C[M,N] = A(bf16)[M,K] @ W(fp32)[N,K]^T (+bias)(+res) ----------------
__global__ __launch_bounds__(256) void gemm_nt_mfma(const short* __restrict__ A,
                                                    const float* __restrict__ W,
                                                    const float* __restrict__ bias,
                                                    const float* __restrict__ res,
                                                    float* __restrict__ C,
                                                    int M, int N, int K) {
  __shared__ __align__(16) short As[128 * 72];
  __shared__ __align__(16) short Bs[128 * 72];
  int tid = threadIdx.x;
  int m0 = blockIdx.y * 128, n0 = blockIdx.x * 128;
  int lane = tid & 63, wid = tid >> 6;
  int wm = (wid & 1) * 64, wn = (wid >> 1) * 64;
  floatx4 acc[4][4] = {};
  for (int k0 = 0; k0 < K; k0 += 64) {
    __syncthreads();
#pragma unroll
    for (int i = 0; i < 4; ++i) {
      int idx = tid + i * 256;
      int m = idx >> 3, c = idx & 7;
      *(int4*)(As + m * 72 + c * 8) = *(const int4*)(A + (size_t)(m0 + m) * K + k0 + c * 8);
    }
#pragma unroll
    for (int i = 0; i < 4; ++i) {
      int idx = tid + i * 256;
      int n = idx >> 3, c = idx & 7;
      const float* wp = W + (size_t)(n0 + n) * K + k0 + c * 8;
      float4 v0 = *(const float4*)(wp);
      float4 v1 = *(const float4*)(wp + 4);
      short8 b;
      b[0] = f2bf(v0.x); b[1] = f2bf(v0.y); b[2] = f2bf(v0.z); b[3] = f2bf(v0.w);
      b[4] = f2bf(v1.x); b[5] = f2bf(v1.y); b[6] = f2bf(v1.z); b[7] = f2bf(v1.w);
      *(short8*)(Bs + n * 72 + c * 8) = b;
    }
    __syncthreads();
#pragma unroll
    for (int ks = 0; ks < 2; ++ks) {
      int ko = ks * 32 + (lane >> 4) * 8;
      short8 af[4], bfg[4];
#pragma unroll
      for (int t = 0; t < 4; ++t)
        af[t] = *(const short8*)(As + (wm + t * 16 + (lane & 15)) * 72 + ko);
#pragma unroll
      for (int t = 0; t < 4; ++t)
        bfg[t] = *(const short8*)(Bs + (wn + t * 16 + (lane & 15)) * 72 + ko);
#pragma unroll
      for (int mt = 0; mt < 4; ++mt)
#pragma unroll
        for (int nt = 0; nt < 4; ++nt)
          acc[mt][nt] = __builtin_amdgcn_mfma_f32_16x16x32_bf16(af[mt], bfg[nt], acc[mt][nt], 0, 0, 0);
    }
  }
  int q = lane >> 4, cl = lane & 15;
#pragma unroll
  for (int mt = 0; mt < 4; ++mt)
#pragma unroll
    for (int nt = 0; nt < 4; ++nt)
#pragma unroll
      for (int r = 0; r < 4; ++r) {
        int m = m0 + wm + mt * 16 + q * 4 + r;
        int n = n0 + wn + nt * 16 + cl;
        float v = acc[mt][nt][r];
        if (bias) v += bias[n];
        if (res) v += res[(size_t)m * N + n];
        C[(size_t)m * N + n] = v;
      }
}

// ---------------- per-head q/k RMSNorm + partial rope, in-place on qkv ----------------
__global__ __launch_bounds__(64) void qknorm_rope(float* __restrict__ qkv,
                                                  const int* __restrict__ positions,
                                                  const float* __restrict__ qn_w,
                                                  const float* __restrict__ kn_w) {
  int t = blockIdx.x;
  int head = blockIdx.y;
  int lane = threadIdx.x;
  int s = t & (S_LEN - 1);
  bool isq = head < NHQ;
  int off = isq ? head * D_HEAD : (NHQ * D_HEAD + (head - NHQ) * D_HEAD);
  float* ptr = qkv + (size_t)t * QKV_DIM + off;
  const float* w = isq ? qn_w : kn_w;
  float x0 = ptr[lane];
  float x1 = ptr[lane + 64];
  float ss = x0 * x0 + x1 * x1;
  for (int i = 1; i < 64; i <<= 1) ss += __shfl_xor(ss, i);
  float rs = rsqrtf(ss / (float)D_HEAD + EPS_F);
  x0 = x0 * rs * w[lane];
  x1 = x1 * rs * w[lane + 64];
  float pos = (float)positions[s];
  int i2 = lane & 31;
  float invf = powf(10000.0f, -(float)i2 / 32.0f);
  float ang = pos * invf;
  float c = cosf(ang), sn = sinf(ang);
  float other = __shfl_xor(x0, 32);
  float r = (lane < 32) ? (x0 * c - other * sn) : (x0 * c + other * sn);
  ptr[lane] = r;
  ptr[lane + 64] = x1;
}

// ---------------- causal GQA attention (fp32 in, bf16 out) ----------------
__global__ __launch_bounds__(256) void attn_kernel(const float* __restrict__ qkv,
                                                   short* __restrict__ attnout) {
  int q = blockIdx.x, h = blockIdx.y, b = blockIdx.z;
  int tid = threadIdx.x;
  __shared__ float qs[D_HEAD];
  __shared__ float ps[S_LEN];
  __shared__ float red[256];
  int kvh = h >> 2;
  const float* qptr = qkv + ((size_t)(b * S_LEN + q)) * QKV_DIM + h * D_HEAD;
  if (tid < D_HEAD) qs[tid] = qptr[tid];
  __syncthreads();
  int nk = q + 1;
  float lmax = -1e30f;
  for (int k = tid; k < nk; k += 256) {
    const float* kptr = qkv + ((size_t)(b * S_LEN + k)) * QKV_DIM + NHQ * D_HEAD + kvh * D_HEAD;
    float sacc = 0.f;
#pragma unroll
    for (int d = 0; d < D_HEAD; d += 4) {
      float4 kv4 = *(const float4*)(kptr + d);
      sacc = fmaf(qs[d], kv4.x, sacc);
      sacc = fmaf(qs[d + 1], kv4.y, sacc);
      sacc = fmaf(qs[d + 2], kv4.z, sacc);
      sacc = fmaf(qs[d + 3], kv4.w, sacc);
    }
    sacc *= SCALE_F;
    ps[k] = sacc;
    lmax = fmaxf(lmax, sacc);
  }
  red[tid] = lmax;
  __syncthreads();
  for (int s2 = 128; s2 > 0; s2 >>= 1) {
    if (tid < s2) red[tid] = fmaxf(red[tid], red[tid + s2]);
    __syncthreads();
  }
  float m = red[0];
  __syncthreads();
  float lsum = 0.f;
  for (int k = tid; k < nk; k += 256) {
    float e = expf(ps[k] - m);
    ps[k] = e;
    lsum += e;
  }
  red[tid] = lsum;
  __syncthreads();
  for (int s2 = 128; s2 > 0; s2 >>= 1) {
    if (tid < s2) red[tid] += red[tid + s2];
    __syncthreads();
  }
  float inv = 1.0f / red[0];
  __syncthreads();
  int d = tid & 127, half = tid >> 7;
  float acc = 0.f;
  for (int k = half; k < nk; k += 2) {
    const float* vptr = qkv + ((size_t)(b * S_LEN + k)) * QKV_DIM + (NHQ + NKV) * D_HEAD + kvh * D_HEAD;
    acc = fmaf(ps[k], vptr[d], acc);
  }
  red[tid] = acc;
  __syncthreads();
  if (tid < 128) {
    float o = (red[tid] + red[tid + 128]) * inv;
    attnout[((size_t)(b * S_LEN + q)) * (NHQ * D_HEAD) + h * D_HEAD + d] = f2bf(o);
  }
}

// ---------------- MoE gating ----------------
__global__ __launch_bounds__(64) void gating_kernel(const float* __restrict__ xt,
                                                    const float* __restrict__ gate_w,
                                                    const float* __restrict__ gate_b,
                                                    int* __restrict__ topi,
                                                    float* __restrict__ fw) {
  __shared__ float xs[H_DIM];
  __shared__ float sc[NE];
  __shared__ float corr[NE];
  __shared__ float grp[NGRP];
  int t = blockIdx.x;
  int e = threadIdx.x;
  for (int i = e; i < H_DIM; i += 64) xs[i] = xt[(size_t)t * H_DIM + i];
  __syncthreads();
  const float* gw = gate_w + (size_t)e * H_DIM;
  float acc = 0.f;
  for (int h = 0; h < H_DIM; ++h) acc = fmaf(xs[h], gw[h], acc);
  float s = 1.f / (1.f + expf(-acc));
  sc[e] = s;
  corr[e] = s + gate_b[e];
  __syncthreads();
  if (e < NGRP) {
    float m1 = -1e30f, m2 = -1e30f;
    for (int j = 0; j < NE / NGRP; ++j) {
      float v = corr[e * 8 + j];
      if (v > m1) { m2 = m1; m1 = v; }
      else if (v > m2) m2 = v;
    }
    grp[e] = m1 + m2;
  }
  __syncthreads();
  if (e == 0) {
    bool gsel[NGRP];
    for (int g = 0; g < NGRP; ++g) gsel[g] = false;
    for (int it = 0; it < TGRP; ++it) {
      int bi = -1; float bv = -1e30f;
      for (int g = 0; g < NGRP; ++g)
        if (!gsel[g] && grp[g] > bv) { bv = grp[g]; bi = g; }
      gsel[bi] = true;
    }
    bool ch[NE];
    for (int i2 = 0; i2 < NE; ++i2) ch[i2] = false;
    int sel[TOPK];
    float wsum = 0.f;
    for (int it = 0; it < TOPK; ++it) {
      int bi = -1; float bv = -1e30f;
      for (int x2 = 0; x2 < NE; ++x2) {
        if (!gsel[x2 >> 3] || ch[x2]) continue;
        if (corr[x2] > bv) { bv = corr[x2]; bi = x2; }
      }
      ch[bi] = true;
      sel[it] = bi;
      wsum += sc[bi];
    }
    float inv = 1.f / wsum;
    for (int it = 0; it < TOPK; ++it) {
      topi[t * TOPK + it] = sel[it];
      fw[t * TOPK + it] = sc[sel[it]] * inv;
    }
  }
}

// ---------------- ordered capacity scan ----------------
__global__ __launch_bounds__(64) void scan_kernel(const int* __restrict__ topi,
                                                  int* __restrict__ perm,
                                                  int* __restrict__ ecnt) {
  int e = threadIdx.x;
  int cnt = 0;
  for (int i = 0; i < T_TOK * TOPK; ++i) {
    if (topi[i] == e) {
      if (cnt < CAP) perm[e * CAP + cnt] = i;
      cnt++;
    }
  }
  ecnt[e] = cnt < CAP ? cnt : CAP;
}

__global__ void zero_kernel(float4* __restrict__ p) {
  p[(size_t)blockIdx.x * 256 + threadIdx.x] = make_float4(0.f, 0.f, 0.f, 0.f);
}

// ---------------- F1: act = silu(X Wg) * (X Wu), MFMA, bf16 out ----------------
// grid.x = 256 routed (e = bx>>2, tile = bx&3) + 16 shared tiles
__global__ __launch_bounds__(256) void moe_gu_mfma(const short* __restrict__ xtb,
                                                   const float* __restrict__ w_gu,
                                                   const float* __restrict__ sw_gu,
                                                   const int* __restrict__ perm,
                                                   const int* __restrict__ ecnt,
                                                   short* __restrict__ actR,
                                                   short* __restrict__ actS) {
  __shared__ int tok[128];
  __shared__ __align__(16) short As[128 * 72];
  __shared__ __align__(16) short Bs[128 * 72];  // B-tiles; reused as G exchange
  int tid = threadIdx.x;
  int bx = blockIdx.x;
  int lane = tid & 63, wid = tid >> 6;
  bool sh = bx >= 256;
  int e = 0, base, rows;
  const float* wg;
  short* actp;
  if (!sh) {
    e = bx >> 2; base = (bx & 3) * 128;
    int cnt = ecnt[e];
    if (base >= cnt) return;
    rows = cnt - base; if (rows > 128) rows = 128;
    wg = w_gu + (size_t)e * H_DIM * (2 * FI_DIM);
    actp = actR + (size_t)(e * CAP + base) * FI_DIM;
  } else {
    base = (bx - 256) * 128; rows = 128;
    wg = sw_gu;
    actp = actS + (size_t)base * FI_DIM;
  }
  if (tid < 128) {
    int m = tid < rows ? tid : (rows - 1);
    tok[tid] = sh ? (base + tid) : (perm[e * CAP + base + m] >> 3);
  }
  __syncthreads();
  int mh = (wid & 1) * 64;
  int uh = wid >> 1;  // 0 -> gate half, 1 -> up half
  for (int jc = 0; jc < 8; ++jc) {
    floatx4 acc[4][4] = {};
    for (int k0 = 0; k0 < H_DIM; k0 += 64) {
      __syncthreads();
#pragma unroll
      for (int i = 0; i < 4; ++i) {
        int idx = tid + i * 256;
        int m = idx >> 3, c = idx & 7;
        *(int4*)(As + m * 72 + c * 8) =
            *(const int4*)(xtb + (size_t)tok[m] * H_DIM + k0 + c * 8);
      }
#pragma unroll
      for (int i = 0; i < 4; ++i) {
        int idx = tid + i * 256;
        int kc = idx >> 7, n2 = idx & 127;
        int col = (n2 < 64) ? (jc * 64 + n2) : (FI_DIM + jc * 64 + (n2 - 64));
        const float* wp = wg + (size_t)(k0 + kc * 8) * (2 * FI_DIM) + col;
        short8 b;
#pragma unroll
        for (int j = 0; j < 8; ++j) b[j] = f2bf(wp[(size_t)j * (2 * FI_DIM)]);
        *(short8*)(Bs + n2 * 72 + kc * 8) = b;
      }
      __syncthreads();
#pragma unroll
      for (int ks = 0; ks < 2; ++ks) {
        int ko = ks * 32 + (lane >> 4) * 8;
        short8 af[4], bfg[4];
#pragma unroll
        for (int t = 0; t < 4; ++t)
          af[t] = *(const short8*)(As + (mh + t * 16 + (lane & 15)) * 72 + ko);
#pragma unroll
        for (int t = 0; t < 4; ++t)
          bfg[t] = *(const short8*)(Bs + (uh * 64 + t * 16 + (lane & 15)) * 72 + ko);
#pragma unroll
        for (int mt = 0; mt < 4; ++mt)
#pragma unroll
          for (int nt = 0; nt < 4; ++nt)
            acc[mt][nt] = __builtin_amdgcn_mfma_f32_16x16x32_bf16(af[mt], bfg[nt], acc[mt][nt], 0, 0, 0);
      }
    }
    __syncthreads();
    int q = lane >> 4, cl = lane & 15;
    if (uh == 0) {  // write gate values (bf16) into Bs[row][col]
#pragma unroll
      for (int mt = 0; mt < 4; ++mt)
#pragma unroll
        for (int nt = 0; nt < 4; ++nt)
#pragma unroll
          for (int r = 0; r < 4; ++r) {
            int row = mh + mt * 16 + q * 4 + r;
            int col = nt * 16 + cl;
            Bs[row * 72 + col] = f2bf(acc[mt][nt][r]);
          }
    }
    __syncthreads();
    if (uh == 1) {
#pragma unroll
      for (int mt = 0; mt < 4; ++mt)
#pragma unroll
        for (int nt = 0; nt < 4; ++nt)
#pragma unroll
          for (int r = 0; r < 4; ++r) {
            int row = mh + mt * 16 + q * 4 + r;
            int col = nt * 16 + cl;
            float g = bf2f(Bs[row * 72 + col]);
            float u = acc[mt][nt][r];
            float a = g / (1.f + expf(-g)) * u;
            actp[(size_t)row * FI_DIM + jc * 64 + col] = f2bf(a);
          }
    }
  }
}

// ---------------- F2: out += (act Wdn) * w, MFMA, atomic scatter ----------------
__global__ __launch_bounds__(256) void moe_dn_mfma(const short* __restrict__ actR,
                                                   const short* __restrict__ actS,
                                                   const float* __restrict__ w_dn,
                                                   const float* __restrict__ sw_dn,
                                                   const int* __restrict__ perm,
                                                   const int* __restrict__ ecnt,
                                                   const float* __restrict__ fw,
                                                   float* __restrict__ moe_acc) {
  __shared__ int tok[128];
  __shared__ float wts[128];
  __shared__ __align__(16) short As[128 * 72];
  __shared__ __align__(16) short Bs[128 * 72];
  int tid = threadIdx.x;
  int bx = blockIdx.x;
  int lane = tid & 63, wid = tid >> 6;
  bool sh = bx >= 256;
  int e = 0, base, rows;
  const float* wd;
  const short* actp;
  if (!sh) {
    e = bx >> 2; base = (bx & 3) * 128;
    int cnt = ecnt[e];
    if (base >= cnt) return;
    rows = cnt - base; if (rows > 128) rows = 128;
    wd = w_dn + (size_t)e * FI_DIM * H_DIM;
    actp = actR + (size_t)(e * CAP + base) * FI_DIM;
  } else {
    base = (bx - 256) * 128; rows = 128;
    wd = sw_dn;
    actp = actS + (size_t)base * FI_DIM;
  }
  if (tid < 128) {
    if (sh) { tok[tid] = base + tid; wts[tid] = 1.f; }
    else if (tid < rows) {
      int pi = perm[e * CAP + base + tid];
      tok[tid] = pi >> 3;
      wts[tid] = fw[pi];
    } else { tok[tid] = 0; wts[tid] = 0.f; }
  }
  __syncthreads();
  int mh = (wid & 1) * 64, wn = (wid >> 1) * 64;
  for (int jc = 0; jc < 8; ++jc) {
    floatx4 acc[4][4] = {};
    for (int k0 = 0; k0 < FI_DIM; k0 += 64) {
      __syncthreads();
#pragma unroll
      for (int i = 0; i < 4; ++i) {
        int idx = tid + i * 256;
        int m = idx >> 3, c = idx & 7;
        *(int4*)(As + m * 72 + c * 8) =
            *(const int4*)(actp + (size_t)m * FI_DIM + k0 + c * 8);
      }
#pragma unroll
      for (int i = 0; i < 4; ++i) {
        int idx = tid + i * 256;
        int kc = idx >> 7, n2 = idx & 127;
        const float* wp = wd + (size_t)(k0 + kc * 8) * H_DIM + jc * 128 + n2;
        short8 b;
#pragma unroll
        for (int j = 0; j < 8; ++j) b[j] = f2bf(wp[(size_t)j * H_DIM]);
        *(short8*)(Bs + n2 * 72 + kc * 8) = b;
      }
      __syncthreads();
#pragma unroll
      for (int ks = 0; ks < 2; ++ks) {
        int ko = ks * 32 + (lane >> 4) * 8;
        short8 af[4], bfg[4];
#pragma unroll
        for (int t = 0; t < 4; ++t)
          af[t] = *(const short8*)(As + (mh + t * 16 + (lane & 15)) * 72 + ko);
#pragma unroll
        for (int t = 0; t < 4; ++t)
          bfg[t] = *(const short8*)(Bs + (wn + t * 16 + (lane & 15)) * 72 + ko);
#pragma unroll
        for (int mt = 0; mt < 4; ++mt)
#pragma unroll
          for (int nt = 0; nt < 4; ++nt)
            acc[mt][nt] = __builtin_amdgcn_mfma_f32_16x16x32_bf16(af[mt], bfg[nt], acc[mt][nt], 0, 0, 0);
      }
    }
    __syncthreads();
    int q = lane >> 4, cl = lane & 15;
#pragma unroll
    for (int mt = 0; mt < 4; ++mt)
#pragma unroll
      for (int nt = 0; nt < 4; ++nt)
#pragma unroll
        for (int r = 0; r < 4; ++r) {
          int row = mh + mt * 16 + q * 4 + r;
          if (row < rows) {
            int col = jc * 128 + wn + nt * 16 + cl;
            unsafeAtomicAdd(moe_acc + (size_t)tok[row] * H_DIM + col,
                            acc[mt][nt][r] * wts[row]);
          }
        }
  }
}

// ---------------- final combine ----------------
__global__ void combine_kernel(const float4* __restrict__ a, const float4* __restrict__ b,
                               float4* __restrict__ o) {
  size_t i = (size_t)blockIdx.x * 256 + threadIdx.x;
  float4 x = a[i], y = b[i];
  o[i] = make_float4(x.x + y.x, x.y + y.y, x.z + y.z, x.w + y.w);
}

extern "C" void kernel_launch(void* const* d_in, const int* in_sizes, int n_in,
                              void* d_out, int out_size, void* d_ws, size_t ws_size,
                              hipStream_t stream) {
  const float* x = (const float*)d_in[0];
  const int* positions = (const int*)d_in[1];
  const float* ln1_w = (const float*)d_in[2];
  const float* ln2_w = (const float*)d_in[3];
  const float* wqkv = (const float*)d_in[4];
  const float* bqkv = (const float*)d_in[5];
  const float* qn_w = (const float*)d_in[6];
  const float* kn_w = (const float*)d_in[7];
  const float* wo = (const float*)d_in[8];
  const float* gate_w = (const float*)d_in[9];
  const float* gate_b = (const float*)d_in[10];
  const float* w_gu = (const float*)d_in[11];
  const float* w_dn = (const float*)d_in[12];
  const float* sw_gu = (const float*)d_in[13];
  const float* sw_dn = (const float*)d_in[14];
  float* out = (float*)d_out;

  float* p = (float*)d_ws;
  float* h2 = p;        p += 2097152;
  float* xt = p;        p += 2097152;
  short* xtb = (short*)p; p += 1048576;
  float* moe_acc = p;   p += 2097152;
  float* fw = p;        p += 16384;
  int* topi = (int*)p;  p += 16384;
  int* perm = (int*)p;  p += 32768;
  int* ecnt = (int*)p;  p += 64;
  float* pool = p;
  // early-phase aliases
  short* h1b = (short*)pool;                 // T*H bf16
  float* qkv = pool + 1048576;               // T*1536 fp32
  short* attnb = (short*)(pool + 4194304);   // T*1024 bf16
  // late-phase aliases (reuse same pool; earlier buffers dead by then)
  short* actR = (short*)pool;                // E*CAP*FI bf16
  short* actS = (short*)(pool + 8388608);    // T*FI bf16

  // 1. rmsnorm(x) -> h1 bf16
  rmsnorm_row<<<T_TOK, 256, 0, stream>>>(x, ln1_w, nullptr, h1b);
  // 2. qkv = h1 @ wqkv^T + bqkv  (MFMA)
  gemm_nt_mfma<<<dim3(QKV_DIM / 128, T_TOK / 128), 256, 0, stream>>>(
      h1b, wqkv, bqkv, nullptr, qkv, T_TOK, QKV_DIM, H_DIM);
  // 3. q/k rmsnorm + rope (fp32, in place)
  qknorm_rope<<<dim3(T_TOK, NHQ + NKV), 64, 0, stream>>>(qkv, positions, qn_w, kn_w);
  // 4. attention -> attnb bf16
  attn_kernel<<<dim3(S_LEN, NHQ, B_SZ), 256, 0, stream>>>(qkv, attnb);
  // 5. h2 = x + attn @ wo^T (MFMA)
  gemm_nt_mfma<<<dim3(H_DIM / 128, T_TOK / 128), 256, 0, stream>>>(
      attnb, wo, nullptr, x, h2, T_TOK, H_DIM, NHQ * D_HEAD);
  // 6. xt = rmsnorm(h2) (fp32 + bf16)
  rmsnorm_row<<<T_TOK, 256, 0, stream>>>(h2, ln2_w, xt, xtb);
  // 7. gating
  gating_kernel<<<T_TOK, 64, 0, stream>>>(xt, gate_w, gate_b, topi, fw);
  // 8. zero MoE accumulator
  zero_kernel<<<2048, 256, 0, stream>>>((float4*)moe_acc);
  // 9. capacity scan
  scan_kernel<<<1, 64, 0, stream>>>(topi, perm, ecnt);
  // 10. F1: gu + silu (routed + shared fused in one grid)
  moe_gu_mfma<<<256 + T_TOK / 128, 256, 0, stream>>>(xtb, w_gu, sw_gu, perm, ecnt, actR, actS);
  // 11. F2: dn + weighted scatter
  moe_dn_mfma<<<256 + T_TOK / 128, 256, 0, stream>>>(actR, actS, w_dn, sw_dn, perm, ecnt, fw, moe_acc);
  // 12. out = h2 + moe
  combine_kernel<<<2048, 256, 0, stream>>>((const float4*)h2, (const float4*)moe_acc, (float4*)out);
}

// Round 3
// 2801.516 us; speedup vs baseline: 2.1964x; 1.4935x over previous
//
#include <hip/hip_runtime.h>
#include <math.h>

#define S_LEN 1024
#define B_SZ 2
#define H_DIM 1024
#define NHQ 8
#define NKV 2
#define D_HEAD 128
#define NE 64
#define TOPK 8
#define NGRP 8
#define TGRP 4
#define FI_DIM 512
#define CAP 512
#define EPS_F 1e-5f
#define T_TOK (B_SZ * S_LEN)               // 2048
#define QKV_DIM ((NHQ + 2 * NKV) * D_HEAD) // 1536
#define SCALE_F 0.08838834764831845f       // 1/sqrt(128)

typedef __attribute__((ext_vector_type(8))) short short8;
typedef __attribute__((ext_vector_type(4))) float floatx4;

__device__ inline short f2bf(float f) {
  union { float f; unsigned u; } v; v.f = f;
  unsigned r = (v.u + 0x7FFFu + ((v.u >> 16) & 1u)) >> 16;
  return (short)(r & 0xFFFFu);
}
__device__ inline float bf2f(short s) {
  union { unsigned u; float f; } v; v.u = ((unsigned)(unsigned short)s) << 16;
  return v.f;
}

// ---------------- RMSNorm: writes bf16 always, fp32 optionally ----------------
__global__ __launch_bounds__(256) void rmsnorm_row(const float* __restrict__ x,
                                                   const float* __restrict__ w,
                                                   float* __restrict__ outf,
                                                   short* __restrict__ outb) {
  int t = blockIdx.x;
  int tid = threadIdx.x;
  const float* xp = x + (size_t)t * H_DIM;
  float4 v = *(const float4*)(xp + tid * 4);
  float ss = v.x * v.x + v.y * v.y + v.z * v.z + v.w * v.w;
  for (int i = 1; i < 64; i <<= 1) ss += __shfl_xor(ss, i);
  __shared__ float red[4];
  if ((tid & 63) == 0) red[tid >> 6] = ss;
  __syncthreads();
  float tot = red[0] + red[1] + red[2] + red[3];
  float rs = rsqrtf(tot / (float)H_DIM + EPS_F);
  float4 wv = *(const float4*)(w + tid * 4);
  float4 o;
  o.x = v.x * rs * wv.x; o.y = v.y * rs * wv.y;
  o.z = v.z * rs * wv.z; o.w = v.w * rs * wv.w;
  if (outf) *(float4*)(outf + (size_t)t * H_DIM + tid * 4) = o;
  short* bp = outb + (size_t)t * H_DIM + tid * 4;
  bp[0] = f2bf(o.x); bp[1] = f2bf(o.y); bp[2] = f2bf(o.z); bp[3] = f2bf(o.w);
}

// ---------------- MFMA NT GEMM: C[M,N] = A(bf16)[M,K] @ W(fp32)[N,K]^T (+bias)(+res) ----------------
__global__ __launch_bounds__(256) void gemm_nt_mfma(const short* __restrict__ A,
                                                    const float* __restrict__ W,
                                                    const float* __restrict__ bias,
                                                    const float* __restrict__ res,
                                                    float* __restrict__ C,
                                                    int M, int N, int K) {
  __shared__ __align__(16) short As[128 * 72];
  __shared__ __align__(16) short Bs[128 * 72];
  int tid = threadIdx.x;
  int m0 = blockIdx.y * 128, n0 = blockIdx.x * 128;
  int lane = tid & 63, wid = tid >> 6;
  int wm = (wid & 1) * 64, wn = (wid >> 1) * 64;
  floatx4 acc[4][4] = {};
  for (int k0 = 0; k0 < K; k0 += 64) {
    __syncthreads();
#pragma unroll
    for (int i = 0; i < 4; ++i) {
      int idx = tid + i * 256;
      int m = idx >> 3, c = idx & 7;
      *(int4*)(As + m * 72 + c * 8) = *(const int4*)(A + (size_t)(m0 + m) * K + k0 + c * 8);
    }
#pragma unroll
    for (int i = 0; i < 4; ++i) {
      int idx = tid + i * 256;
      int n = idx >> 3, c = idx & 7;
      const float* wp = W + (size_t)(n0 + n) * K + k0 + c * 8;
      float4 v0 = *(const float4*)(wp);
      float4 v1 = *(const float4*)(wp + 4);
      short8 b;
      b[0] = f2bf(v0.x); b[1] = f2bf(v0.y); b[2] = f2bf(v0.z); b[3] = f2bf(v0.w);
      b[4] = f2bf(v1.x); b[5] = f2bf(v1.y); b[6] = f2bf(v1.z); b[7] = f2bf(v1.w);
      *(short8*)(Bs + n * 72 + c * 8) = b;
    }
    __syncthreads();
#pragma unroll
    for (int ks = 0; ks < 2; ++ks) {
      int ko = ks * 32 + (lane >> 4) * 8;
      short8 af[4], bfg[4];
#pragma unroll
      for (int t = 0; t < 4; ++t)
        af[t] = *(const short8*)(As + (wm + t * 16 + (lane & 15)) * 72 + ko);
#pragma unroll
      for (int t = 0; t < 4; ++t)
        bfg[t] = *(const short8*)(Bs + (wn + t * 16 + (lane & 15)) * 72 + ko);
#pragma unroll
      for (int mt = 0; mt < 4; ++mt)
#pragma unroll
        for (int nt = 0; nt < 4; ++nt)
          acc[mt][nt] = __builtin_amdgcn_mfma_f32_16x16x32_bf16(af[mt], bfg[nt], acc[mt][nt], 0, 0, 0);
    }
  }
  int q = lane >> 4, cl = lane & 15;
#pragma unroll
  for (int mt = 0; mt < 4; ++mt)
#pragma unroll
    for (int nt = 0; nt < 4; ++nt)
#pragma unroll
      for (int r = 0; r < 4; ++r) {
        int m = m0 + wm + mt * 16 + q * 4 + r;
        int n = n0 + wn + nt * 16 + cl;
        float v = acc[mt][nt][r];
        if (bias) v += bias[n];
        if (res) v += res[(size_t)m * N + n];
        C[(size_t)m * N + n] = v;
      }
}

// ---------------- per-head q/k RMSNorm + partial rope, in-place on qkv ----------------
__global__ __launch_bounds__(64) void qknorm_rope(float* __restrict__ qkv,
                                                  const int* __restrict__ positions,
                                                  const float* __restrict__ qn_w,
                                                  const float* __restrict__ kn_w) {
  int t = blockIdx.x;
  int head = blockIdx.y;
  int lane = threadIdx.x;
  int s = t & (S_LEN - 1);
  bool isq = head < NHQ;
  int off = isq ? head * D_HEAD : (NHQ * D_HEAD + (head - NHQ) * D_HEAD);
  float* ptr = qkv + (size_t)t * QKV_DIM + off;
  const float* w = isq ? qn_w : kn_w;
  float x0 = ptr[lane];
  float x1 = ptr[lane + 64];
  float ss = x0 * x0 + x1 * x1;
  for (int i = 1; i < 64; i <<= 1) ss += __shfl_xor(ss, i);
  float rs = rsqrtf(ss / (float)D_HEAD + EPS_F);
  x0 = x0 * rs * w[lane];
  x1 = x1 * rs * w[lane + 64];
  float pos = (float)positions[s];
  int i2 = lane & 31;
  float invf = powf(10000.0f, -(float)i2 / 32.0f);
  float ang = pos * invf;
  float c = cosf(ang), sn = sinf(ang);
  float other = __shfl_xor(x0, 32);
  float r = (lane < 32) ? (x0 * c - other * sn) : (x0 * c + other * sn);
  ptr[lane] = r;
  ptr[lane + 64] = x1;
}

// ---------------- causal GQA attention (fp32 in, bf16 out) ----------------
__global__ __launch_bounds__(256) void attn_kernel(const float* __restrict__ qkv,
                                                   short* __restrict__ attnout) {
  int q = blockIdx.x, h = blockIdx.y, b = blockIdx.z;
  int tid = threadIdx.x;
  __shared__ float qs[D_HEAD];
  __shared__ float ps[S_LEN];
  __shared__ float red[256];
  int kvh = h >> 2;
  const float* qptr = qkv + ((size_t)(b * S_LEN + q)) * QKV_DIM + h * D_HEAD;
  if (tid < D_HEAD) qs[tid] = qptr[tid];
  __syncthreads();
  int nk = q + 1;
  float lmax = -1e30f;
  for (int k = tid; k < nk; k += 256) {
    const float* kptr = qkv + ((size_t)(b * S_LEN + k)) * QKV_DIM + NHQ * D_HEAD + kvh * D_HEAD;
    float sacc = 0.f;
#pragma unroll
    for (int d = 0; d < D_HEAD; d += 4) {
      float4 kv4 = *(const float4*)(kptr + d);
      sacc = fmaf(qs[d], kv4.x, sacc);
      sacc = fmaf(qs[d + 1], kv4.y, sacc);
      sacc = fmaf(qs[d + 2], kv4.z, sacc);
      sacc = fmaf(qs[d + 3], kv4.w, sacc);
    }
    sacc *= SCALE_F;
    ps[k] = sacc;
    lmax = fmaxf(lmax, sacc);
  }
  red[tid] = lmax;
  __syncthreads();
  for (int s2 = 128; s2 > 0; s2 >>= 1) {
    if (tid < s2) red[tid] = fmaxf(red[tid], red[tid + s2]);
    __syncthreads();
  }
  float m = red[0];
  __syncthreads();
  float lsum = 0.f;
  for (int k = tid; k < nk; k += 256) {
    float e = expf(ps[k] - m);
    ps[k] = e;
    lsum += e;
  }
  red[tid] = lsum;
  __syncthreads();
  for (int s2 = 128; s2 > 0; s2 >>= 1) {
    if (tid < s2) red[tid] += red[tid + s2];
    __syncthreads();
  }
  float inv = 1.0f / red[0];
  __syncthreads();
  int d = tid & 127, half = tid >> 7;
  float acc = 0.f;
  for (int k = half; k < nk; k += 2) {
    const float* vptr = qkv + ((size_t)(b * S_LEN + k)) * QKV_DIM + (NHQ + NKV) * D_HEAD + kvh * D_HEAD;
    acc = fmaf(ps[k], vptr[d], acc);
  }
  red[tid] = acc;
  __syncthreads();
  if (tid < 128) {
    float o = (red[tid] + red[tid + 128]) * inv;
    attnout[((size_t)(b * S_LEN + q)) * (NHQ * D_HEAD) + h * D_HEAD + d] = f2bf(o);
  }
}

// ---------------- MoE gating ----------------
__global__ __launch_bounds__(64) void gating_kernel(const float* __restrict__ xt,
                                                    const float* __restrict__ gate_w,
                                                    const float* __restrict__ gate_b,
                                                    int* __restrict__ topi,
                                                    float* __restrict__ fw) {
  __shared__ float xs[H_DIM];
  __shared__ float sc[NE];
  __shared__ float corr[NE];
  __shared__ float grp[NGRP];
  int t = blockIdx.x;
  int e = threadIdx.x;
  for (int i = e; i < H_DIM; i += 64) xs[i] = xt[(size_t)t * H_DIM + i];
  __syncthreads();
  const float* gw = gate_w + (size_t)e * H_DIM;
  float acc = 0.f;
  for (int h = 0; h < H_DIM; ++h) acc = fmaf(xs[h], gw[h], acc);
  float s = 1.f / (1.f + expf(-acc));
  sc[e] = s;
  corr[e] = s + gate_b[e];
  __syncthreads();
  if (e < NGRP) {
    float m1 = -1e30f, m2 = -1e30f;
    for (int j = 0; j < NE / NGRP; ++j) {
      float v = corr[e * 8 + j];
      if (v > m1) { m2 = m1; m1 = v; }
      else if (v > m2) m2 = v;
    }
    grp[e] = m1 + m2;
  }
  __syncthreads();
  if (e == 0) {
    bool gsel[NGRP];
    for (int g = 0; g < NGRP; ++g) gsel[g] = false;
    for (int it = 0; it < TGRP; ++it) {
      int bi = -1; float bv = -1e30f;
      for (int g = 0; g < NGRP; ++g)
        if (!gsel[g] && grp[g] > bv) { bv = grp[g]; bi = g; }
      gsel[bi] = true;
    }
    bool ch[NE];
    for (int i2 = 0; i2 < NE; ++i2) ch[i2] = false;
    int sel[TOPK];
    float wsum = 0.f;
    for (int it = 0; it < TOPK; ++it) {
      int bi = -1; float bv = -1e30f;
      for (int x2 = 0; x2 < NE; ++x2) {
        if (!gsel[x2 >> 3] || ch[x2]) continue;
        if (corr[x2] > bv) { bv = corr[x2]; bi = x2; }
      }
      ch[bi] = true;
      sel[it] = bi;
      wsum += sc[bi];
    }
    float inv = 1.f / wsum;
    for (int it = 0; it < TOPK; ++it) {
      topi[t * TOPK + it] = sel[it];
      fw[t * TOPK + it] = sc[sel[it]] * inv;
    }
  }
}

// ---------------- parallel ordered capacity scan: 1 block, 256 threads ----------------
// Stable counting-rank over flat (token-major, k-order) index. Stride-65 LDS
// so bank = (chunk + expert) % 32 -> spread even under expert skew.
__global__ __launch_bounds__(256) void scan_kernel(const int* __restrict__ topi,
                                                   int* __restrict__ perm,
                                                   int* __restrict__ ecnt) {
  __shared__ int hist[256 * 65];
  int tid = threadIdx.x;
  for (int i = tid; i < 256 * 65; i += 256) hist[i] = 0;
  __syncthreads();
  // phase 1: per-chunk histogram (chunk = 64 consecutive flat entries)
  int loc[64];
#pragma unroll
  for (int j = 0; j < 64; j += 4) {
    int4 v = *(const int4*)(topi + tid * 64 + j);
    loc[j] = v.x; loc[j + 1] = v.y; loc[j + 2] = v.z; loc[j + 3] = v.w;
  }
#pragma unroll
  for (int j = 0; j < 64; ++j) hist[tid * 65 + loc[j]]++;
  __syncthreads();
  // phase 2: exclusive prefix over chunks, one expert per lane (threads 0..63)
  if (tid < 64) {
    int run = 0;
    for (int c = 0; c < 256; ++c) {
      int v = hist[c * 65 + tid];
      hist[c * 65 + tid] = run;
      run += v;
    }
    ecnt[tid] = run < CAP ? run : CAP;
  }
  __syncthreads();
  // phase 3: assign positions in flat order
#pragma unroll
  for (int j = 0; j < 64; ++j) {
    int e = loc[j];
    int pos = hist[tid * 65 + e]++;
    if (pos < CAP) perm[e * CAP + pos] = tid * 64 + j;
  }
}

__global__ void zero_kernel(float4* __restrict__ p) {
  p[(size_t)blockIdx.x * 256 + threadIdx.x] = make_float4(0.f, 0.f, 0.f, 0.f);
}

// ---------------- F1: act = silu(X Wg) * (X Wu), MFMA, bf16 out ----------------
// grid.x = 256 routed (e = bx>>2, tile = bx&3) + 16 shared tiles
__global__ __launch_bounds__(256) void moe_gu_mfma(const short* __restrict__ xtb,
                                                   const float* __restrict__ w_gu,
                                                   const float* __restrict__ sw_gu,
                                                   const int* __restrict__ perm,
                                                   const int* __restrict__ ecnt,
                                                   short* __restrict__ actR,
                                                   short* __restrict__ actS) {
  __shared__ int tok[128];
  __shared__ __align__(16) short As[128 * 72];
  __shared__ __align__(16) short Bs[128 * 72];  // B-tiles; reused as G exchange
  int tid = threadIdx.x;
  int bx = blockIdx.x;
  int lane = tid & 63, wid = tid >> 6;
  bool sh = bx >= 256;
  int e = 0, base, rows;
  const float* wg;
  short* actp;
  if (!sh) {
    e = bx >> 2; base = (bx & 3) * 128;
    int cnt = ecnt[e];
    if (base >= cnt) return;
    rows = cnt - base; if (rows > 128) rows = 128;
    wg = w_gu + (size_t)e * H_DIM * (2 * FI_DIM);
    actp = actR + (size_t)(e * CAP + base) * FI_DIM;
  } else {
    base = (bx - 256) * 128; rows = 128;
    wg = sw_gu;
    actp = actS + (size_t)base * FI_DIM;
  }
  if (tid < 128) {
    int m = tid < rows ? tid : (rows - 1);
    tok[tid] = sh ? (base + tid) : (perm[e * CAP + base + m] >> 3);
  }
  __syncthreads();
  int mh = (wid & 1) * 64;
  int uh = wid >> 1;  // 0 -> gate half, 1 -> up half
  for (int jc = 0; jc < 8; ++jc) {
    floatx4 acc[4][4] = {};
    for (int k0 = 0; k0 < H_DIM; k0 += 64) {
      __syncthreads();
#pragma unroll
      for (int i = 0; i < 4; ++i) {
        int idx = tid + i * 256;
        int m = idx >> 3, c = idx & 7;
        *(int4*)(As + m * 72 + c * 8) =
            *(const int4*)(xtb + (size_t)tok[m] * H_DIM + k0 + c * 8);
      }
#pragma unroll
      for (int i = 0; i < 4; ++i) {
        int idx = tid + i * 256;
        int kc = idx >> 7, n2 = idx & 127;
        int col = (n2 < 64) ? (jc * 64 + n2) : (FI_DIM + jc * 64 + (n2 - 64));
        const float* wp = wg + (size_t)(k0 + kc * 8) * (2 * FI_DIM) + col;
        short8 b;
#pragma unroll
        for (int j = 0; j < 8; ++j) b[j] = f2bf(wp[(size_t)j * (2 * FI_DIM)]);
        *(short8*)(Bs + n2 * 72 + kc * 8) = b;
      }
      __syncthreads();
#pragma unroll
      for (int ks = 0; ks < 2; ++ks) {
        int ko = ks * 32 + (lane >> 4) * 8;
        short8 af[4], bfg[4];
#pragma unroll
        for (int t = 0; t < 4; ++t)
          af[t] = *(const short8*)(As + (mh + t * 16 + (lane & 15)) * 72 + ko);
#pragma unroll
        for (int t = 0; t < 4; ++t)
          bfg[t] = *(const short8*)(Bs + (uh * 64 + t * 16 + (lane & 15)) * 72 + ko);
#pragma unroll
        for (int mt = 0; mt < 4; ++mt)
#pragma unroll
          for (int nt = 0; nt < 4; ++nt)
            acc[mt][nt] = __builtin_amdgcn_mfma_f32_16x16x32_bf16(af[mt], bfg[nt], acc[mt][nt], 0, 0, 0);
      }
    }
    __syncthreads();
    int q = lane >> 4, cl = lane & 15;
    if (uh == 0) {  // write gate values (bf16) into Bs[row][col]
#pragma unroll
      for (int mt = 0; mt < 4; ++mt)
#pragma unroll
        for (int nt = 0; nt < 4; ++nt)
#pragma unroll
          for (int r = 0; r < 4; ++r) {
            int row = mh + mt * 16 + q * 4 + r;
            int col = nt * 16 + cl;
            Bs[row * 72 + col] = f2bf(acc[mt][nt][r]);
          }
    }
    __syncthreads();
    if (uh == 1) {
#pragma unroll
      for (int mt = 0; mt < 4; ++mt)
#pragma unroll
        for (int nt = 0; nt < 4; ++nt)
#pragma unroll
          for (int r = 0; r < 4; ++r) {
            int row = mh + mt * 16 + q * 4 + r;
            int col = nt * 16 + cl;
            float g = bf2f(Bs[row * 72 + col]);
            float u = acc[mt][nt][r];
            float a = g / (1.f + expf(-g)) * u;
            actp[(size_t)row * FI_DIM + jc * 64 + col] = f2bf(a);
          }
    }
  }
}

// ---------------- F2: out += (act Wdn) * w, MFMA, atomic scatter ----------------
__global__ __launch_bounds__(256) void moe_dn_mfma(const short* __restrict__ actR,
                                                   const short* __restrict__ actS,
                                                   const float* __restrict__ w_dn,
                                                   const float* __restrict__ sw_dn,
                                                   const int* __restrict__ perm,
                                                   const int* __restrict__ ecnt,
                                                   const float* __restrict__ fw,
                                                   float* __restrict__ moe_acc) {
  __shared__ int tok[128];
  __shared__ float wts[128];
  __shared__ __align__(16) short As[128 * 72];
  __shared__ __align__(16) short Bs[128 * 72];
  int tid = threadIdx.x;
  int bx = blockIdx.x;
  int lane = tid & 63, wid = tid >> 6;
  bool sh = bx >= 256;
  int e = 0, base, rows;
  const float* wd;
  const short* actp;
  if (!sh) {
    e = bx >> 2; base = (bx & 3) * 128;
    int cnt = ecnt[e];
    if (base >= cnt) return;
    rows = cnt - base; if (rows > 128) rows = 128;
    wd = w_dn + (size_t)e * FI_DIM * H_DIM;
    actp = actR + (size_t)(e * CAP + base) * FI_DIM;
  } else {
    base = (bx - 256) * 128; rows = 128;
    wd = sw_dn;
    actp = actS + (size_t)base * FI_DIM;
  }
  if (tid < 128) {
    if (sh) { tok[tid] = base + tid; wts[tid] = 1.f; }
    else if (tid < rows) {
      int pi = perm[e * CAP + base + tid];
      tok[tid] = pi >> 3;
      wts[tid] = fw[pi];
    } else { tok[tid] = 0; wts[tid] = 0.f; }
  }
  __syncthreads();
  int mh = (wid & 1) * 64, wn = (wid >> 1) * 64;
  for (int jc = 0; jc < 8; ++jc) {
    floatx4 acc[4][4] = {};
    for (int k0 = 0; k0 < FI_DIM; k0 += 64) {
      __syncthreads();
#pragma unroll
      for (int i = 0; i < 4; ++i) {
        int idx = tid + i * 256;
        int m = idx >> 3, c = idx & 7;
        *(int4*)(As + m * 72 + c * 8) =
            *(const int4*)(actp + (size_t)m * FI_DIM + k0 + c * 8);
      }
#pragma unroll
      for (int i = 0; i < 4; ++i) {
        int idx = tid + i * 256;
        int kc = idx >> 7, n2 = idx & 127;
        const float* wp = wd + (size_t)(k0 + kc * 8) * H_DIM + jc * 128 + n2;
        short8 b;
#pragma unroll
        for (int j = 0; j < 8; ++j) b[j] = f2bf(wp[(size_t)j * H_DIM]);
        *(short8*)(Bs + n2 * 72 + kc * 8) = b;
      }
      __syncthreads();
#pragma unroll
      for (int ks = 0; ks < 2; ++ks) {
        int ko = ks * 32 + (lane >> 4) * 8;
        short8 af[4], bfg[4];
#pragma unroll
        for (int t = 0; t < 4; ++t)
          af[t] = *(const short8*)(As + (mh + t * 16 + (lane & 15)) * 72 + ko);
#pragma unroll
        for (int t = 0; t < 4; ++t)
          bfg[t] = *(const short8*)(Bs + (wn + t * 16 + (lane & 15)) * 72 + ko);
#pragma unroll
        for (int mt = 0; mt < 4; ++mt)
#pragma unroll
          for (int nt = 0; nt < 4; ++nt)
            acc[mt][nt] = __builtin_amdgcn_mfma_f32_16x16x32_bf16(af[mt], bfg[nt], acc[mt][nt], 0, 0, 0);
      }
    }
    __syncthreads();
    int q = lane >> 4, cl = lane & 15;
#pragma unroll
    for (int mt = 0; mt < 4; ++mt)
#pragma unroll
      for (int nt = 0; nt < 4; ++nt)
#pragma unroll
        for (int r = 0; r < 4; ++r) {
          int row = mh + mt * 16 + q * 4 + r;
          if (row < rows) {
            int col = jc * 128 + wn + nt * 16 + cl;
            unsafeAtomicAdd(moe_acc + (size_t)tok[row] * H_DIM + col,
                            acc[mt][nt][r] * wts[row]);
          }
        }
  }
}

// ---------------- final combine ----------------
__global__ void combine_kernel(const float4* __restrict__ a, const float4* __restrict__ b,
                               float4* __restrict__ o) {
  size_t i = (size_t)blockIdx.x * 256 + threadIdx.x;
  float4 x = a[i], y = b[i];
  o[i] = make_float4(x.x + y.x, x.y + y.y, x.z + y.z, x.w + y.w);
}

extern "C" void kernel_launch(void* const* d_in, const int* in_sizes, int n_in,
                              void* d_out, int out_size, void* d_ws, size_t ws_size,
                              hipStream_t stream) {
  const float* x = (const float*)d_in[0];
  const int* positions = (const int*)d_in[1];
  const float* ln1_w = (const float*)d_in[2];
  const float* ln2_w = (const float*)d_in[3];
  const float* wqkv = (const float*)d_in[4];
  const float* bqkv = (const float*)d_in[5];
  const float* qn_w = (const float*)d_in[6];
  const float* kn_w = (const float*)d_in[7];
  const float* wo = (const float*)d_in[8];
  const float* gate_w = (const float*)d_in[9];
  const float* gate_b = (const float*)d_in[10];
  const float* w_gu = (const float*)d_in[11];
  const float* w_dn = (const float*)d_in[12];
  const float* sw_gu = (const float*)d_in[13];
  const float* sw_dn = (const float*)d_in[14];
  float* out = (float*)d_out;

  float* p = (float*)d_ws;
  float* h2 = p;        p += 2097152;
  float* xt = p;        p += 2097152;
  short* xtb = (short*)p; p += 1048576;
  float* moe_acc = p;   p += 2097152;
  float* fw = p;        p += 16384;
  int* topi = (int*)p;  p += 16384;
  int* perm = (int*)p;  p += 32768;
  int* ecnt = (int*)p;  p += 64;
  float* pool = p;
  // early-phase aliases
  short* h1b = (short*)pool;                 // T*H bf16
  float* qkv = pool + 1048576;               // T*1536 fp32
  short* attnb = (short*)(pool + 4194304);   // T*1024 bf16
  // late-phase aliases (reuse same pool; earlier buffers dead by then)
  short* actR = (short*)pool;                // E*CAP*FI bf16
  short* actS = (short*)(pool + 8388608);    // T*FI bf16

  // 1. rmsnorm(x) -> h1 bf16
  rmsnorm_row<<<T_TOK, 256, 0, stream>>>(x, ln1_w, nullptr, h1b);
  // 2. qkv = h1 @ wqkv^T + bqkv  (MFMA)
  gemm_nt_mfma<<<dim3(QKV_DIM / 128, T_TOK / 128), 256, 0, stream>>>(
      h1b, wqkv, bqkv, nullptr, qkv, T_TOK, QKV_DIM, H_DIM);
  // 3. q/k rmsnorm + rope (fp32, in place)
  qknorm_rope<<<dim3(T_TOK, NHQ + NKV), 64, 0, stream>>>(qkv, positions, qn_w, kn_w);
  // 4. attention -> attnb bf16
  attn_kernel<<<dim3(S_LEN, NHQ, B_SZ), 256, 0, stream>>>(qkv, attnb);
  // 5. h2 = x + attn @ wo^T (MFMA)
  gemm_nt_mfma<<<dim3(H_DIM / 128, T_TOK / 128), 256, 0, stream>>>(
      attnb, wo, nullptr, x, h2, T_TOK, H_DIM, NHQ * D_HEAD);
  // 6. xt = rmsnorm(h2) (fp32 + bf16)
  rmsnorm_row<<<T_TOK, 256, 0, stream>>>(h2, ln2_w, xt, xtb);
  // 7. gating
  gating_kernel<<<T_TOK, 64, 0, stream>>>(xt, gate_w, gate_b, topi, fw);
  // 8. zero MoE accumulator
  zero_kernel<<<2048, 256, 0, stream>>>((float4*)moe_acc);
  // 9. parallel capacity scan
  scan_kernel<<<1, 256, 0, stream>>>(topi, perm, ecnt);
  // 10. F1: gu + silu (routed + shared fused in one grid)
  moe_gu_mfma<<<256 + T_TOK / 128, 256, 0, stream>>>(xtb, w_gu, sw_gu, perm, ecnt, actR, actS);
  // 11. F2: dn + weighted scatter
  moe_dn_mfma<<<256 + T_TOK / 128, 256, 0, stream>>>(actR, actS, w_dn, sw_dn, perm, ecnt, fw, moe_acc);
  // 12. out = h2 + moe
  combine_kernel<<<2048, 256, 0, stream>>>((const float4*)h2, (const float4*)moe_acc, (float4*)out);
}